// Round 13
// baseline (174.320 us; speedup 1.0000x reference)
//
#include <hip/hip_runtime.h>
#include <cfloat>
#include <cmath>
#include <cstdint>

#define VV 50257
#define SPLITS 8
#define CHUNKA 6284                      // multiple of 4; 8*6284 >= 50257; last len 6269
#define BMW ((CHUNKA + 31) / 32)         // 197
#define CAPC 512
#define K1T 512
#define NWAVE (K1T / 64)                 // 8
#define SLOTW 80                         // u64 per slot: [0..63] keys, [64] S bits; 640B = 5 cache lines
#define CEXP 28.0f                       // fixed softmax shift; |penalized logit| <~ 23

__device__ __forceinline__ unsigned fmono(float f) {
    unsigned b = __float_as_uint(f);
    return b ^ (((int)b < 0) ? 0xFFFFFFFFu : 0x80000000u);
}
__device__ __forceinline__ float unmono(unsigned m) {
    unsigned b = (m & 0x80000000u) ? (m ^ 0x80000000u) : ~m;
    return __uint_as_float(b);
}
// sortable key: value-desc, tie -> smaller index first; > 0 for finite x
__device__ __forceinline__ uint64_t mkkey(unsigned mono, int idx) {
    return ((uint64_t)mono << 32) | (unsigned)(~idx);
}

// ONE kernel. Per (row, chunk): read-only pass {penalize, exp-sum, top-1};
// theta = 64th of 512 thread maxima (wave bitonic + binsearch); collect >= theta
// via L3-hot re-read; rank-select -> sorted top-64 + S into line-padded slot.
// Last-finishing block of each row (atomic election) inlines the merge/finale
// AND is the sole writer of that row's probs (zero + scatter) and idx.
__global__ __launch_bounds__(K1T) void pp_fused(
    const float* __restrict__ logits, const int* __restrict__ prev,
    const float* __restrict__ rpp, const float* __restrict__ u,
    const float* __restrict__ toppp, const float* __restrict__ tempp,
    const int* __restrict__ topkp,
    uint64_t* __restrict__ slots, int* __restrict__ cnt,
    float* __restrict__ out_idx, float* __restrict__ out_probs, int Hp)
{
    const int sp = blockIdx.x, row = blockIdx.y;
    const int tid = threadIdx.x, lane = tid & 63, wid = tid >> 6;
    const int c0 = sp * CHUNKA;
    const int c1 = min(VV, c0 + CHUNKA);
    const int len = c1 - c0;
    const float rp = rpp[0], inv_rp = 1.0f / rp;

    __shared__ unsigned bm[BMW];
    __shared__ uint64_t kls[K1T];        // NWAVE sorted (desc) 64-lists of maxima
    __shared__ uint64_t cand[CAPC];
    __shared__ uint64_t top64[64];
    __shared__ float red_s[NWAVE];
    __shared__ float sSv;
    __shared__ uint64_t sV64;
    __shared__ int sCnt, sCnt2, sOld;
    __shared__ uint64_t ck[SPLITS * 64];
    __shared__ uint64_t tk[64];
    __shared__ float sS2;

    for (int i = tid; i < BMW; i += K1T) bm[i] = 0u;
    if (tid == 0) sCnt = 0;
    __syncthreads();

    // chunk-local prev-token bitmap (penalty idempotent w.r.t. duplicates)
    const int* prow = prev + (size_t)row * Hp;
    const int h4 = Hp >> 2;
    const int4* prow4 = (const int4*)prow;
    for (int i = tid; i < h4; i += K1T) {
        int4 t4 = prow4[i];
        int t;
        t = t4.x; if (t >= c0 && t < c1) { int o = t - c0; atomicOr(&bm[o >> 5], 1u << (o & 31)); }
        t = t4.y; if (t >= c0 && t < c1) { int o = t - c0; atomicOr(&bm[o >> 5], 1u << (o & 31)); }
        t = t4.z; if (t >= c0 && t < c1) { int o = t - c0; atomicOr(&bm[o >> 5], 1u << (o & 31)); }
        t = t4.w; if (t >= c0 && t < c1) { int o = t - c0; atomicOr(&bm[o >> 5], 1u << (o & 31)); }
    }
    for (int i = 4 * h4 + tid; i < Hp; i += K1T) {
        int t = prow[i];
        if (t >= c0 && t < c1) { int o = t - c0; atomicOr(&bm[o >> 5], 1u << (o & 31)); }
    }
    __syncthreads();

    const float* lrow = logits + (size_t)row * VV;
    // (row*VV + c0) mod 4 == row mod 4  (VV%4==1, CHUNKA%4==0); peel to 16B
    const int pad = (4 - (row & 3)) & 3;
    const int n4 = (len - pad) >> 2;
    const int tail0 = pad + 4 * n4;                 // chunk-local
    const float4* l4 = (const float4*)(lrow + c0 + pad);

    // penalized key at chunk-local offset o (L3-hot helper)
    auto keyAt = [&](int o) -> uint64_t {
        float x = lrow[c0 + o];
        if ((bm[o >> 5] >> (o & 31)) & 1u) x = (x < 0.f) ? x * rp : x * inv_rp;
        return mkkey(fmono(x), c0 + o);
    };

    // ---- pass A (read-only): penalize + fixed-shift exp-sum + top-1 ----
    float s = 0.0f;
    uint64_t k0 = 0ull;
    for (int o = tid; o < pad; o += K1T) {
        float x = lrow[c0 + o];
        if ((bm[o >> 5] >> (o & 31)) & 1u) x = (x < 0.f) ? x * rp : x * inv_rp;
        s += __expf(x - CEXP);
        uint64_t a = mkkey(fmono(x), c0 + o);
        k0 = (a > k0) ? a : k0;
    }
    #pragma unroll 4
    for (int k = tid; k < n4; k += K1T) {
        float4 v = l4[k];
        const int ob = pad + 4 * k;
        float x;
        x = v.x; if ((bm[(ob+0) >> 5] >> ((ob+0) & 31)) & 1u) x = (x < 0.f) ? x * rp : x * inv_rp;
        s += __expf(x - CEXP);
        { uint64_t a = mkkey(fmono(x), c0 + ob + 0); k0 = (a > k0) ? a : k0; }
        x = v.y; if ((bm[(ob+1) >> 5] >> ((ob+1) & 31)) & 1u) x = (x < 0.f) ? x * rp : x * inv_rp;
        s += __expf(x - CEXP);
        { uint64_t a = mkkey(fmono(x), c0 + ob + 1); k0 = (a > k0) ? a : k0; }
        x = v.z; if ((bm[(ob+2) >> 5] >> ((ob+2) & 31)) & 1u) x = (x < 0.f) ? x * rp : x * inv_rp;
        s += __expf(x - CEXP);
        { uint64_t a = mkkey(fmono(x), c0 + ob + 2); k0 = (a > k0) ? a : k0; }
        x = v.w; if ((bm[(ob+3) >> 5] >> ((ob+3) & 31)) & 1u) x = (x < 0.f) ? x * rp : x * inv_rp;
        s += __expf(x - CEXP);
        { uint64_t a = mkkey(fmono(x), c0 + ob + 3); k0 = (a > k0) ? a : k0; }
    }
    for (int o = tail0 + tid; o < len; o += K1T) {
        float x = lrow[c0 + o];
        if ((bm[o >> 5] >> (o & 31)) & 1u) x = (x < 0.f) ? x * rp : x * inv_rp;
        s += __expf(x - CEXP);
        uint64_t a = mkkey(fmono(x), c0 + o);
        k0 = (a > k0) ? a : k0;
    }

    // ---- exp-sum wave reduce ----
    #pragma unroll
    for (int off = 32; off; off >>= 1) s += __shfl_down(s, off);
    if (lane == 0) red_s[wid] = s;

    // ---- wave bitonic sort of k0 across 64 lanes (registers only) ----
    {
        uint64_t v = k0;
        #pragma unroll
        for (int kk = 2; kk <= 64; kk <<= 1) {
            #pragma unroll
            for (int j = kk >> 1; j > 0; j >>= 1) {
                uint64_t o = __shfl_xor(v, j);
                bool lower = (lane & j) == 0;
                bool asc = (lane & kk) == 0;
                uint64_t mx = (v > o) ? v : o;
                uint64_t mn = (v > o) ? o : v;
                v = (lower != asc) ? mx : mn;
            }
        }
        kls[wid * 64 + (63 - lane)] = v;   // store descending
    }
    __syncthreads();
    if (tid == 0) {
        float S = red_s[0];
        #pragma unroll
        for (int w = 1; w < NWAVE; ++w) S += red_s[w];
        sSv = S;
    }

    // ---- theta = 64th-largest thread max: binsearch-rank over 8 sorted lists ----
    {
        const uint64_t ki = kls[tid];
        int r = tid & 63;                 // rank within own (desc) list
        const int j = tid >> 6;
        #pragma unroll
        for (int o = 0; o < NWAVE; ++o) {
            if (o == j) continue;
            const uint64_t* ls = &kls[o * 64];
            int lo = 0, hi = 64;
            while (lo < hi) {             // first idx with ls[idx] < ki (keys unique)
                int mid = (lo + hi) >> 1;
                if (ls[mid] > ki) lo = mid + 1; else hi = mid;
            }
            r += lo;
        }
        if (r == 63) sV64 = ki;           // exactly one thread matches
    }
    __syncthreads();
    const uint64_t th = sV64;

    // ---- collect >= theta (L3-hot vectorized re-read) ----
    for (int o = tid; o < pad; o += K1T) {
        uint64_t a = keyAt(o);
        if (a >= th) { int p = atomicAdd(&sCnt, 1); if (p < CAPC) cand[p] = a; }
    }
    #pragma unroll 2
    for (int k = tid; k < n4; k += K1T) {
        float4 v = l4[k];
        const int ob = pad + 4 * k;
        float x;
        x = v.x; if ((bm[(ob+0) >> 5] >> ((ob+0) & 31)) & 1u) x = (x < 0.f) ? x * rp : x * inv_rp;
        { uint64_t a = mkkey(fmono(x), c0 + ob + 0); if (a >= th) { int p = atomicAdd(&sCnt, 1); if (p < CAPC) cand[p] = a; } }
        x = v.y; if ((bm[(ob+1) >> 5] >> ((ob+1) & 31)) & 1u) x = (x < 0.f) ? x * rp : x * inv_rp;
        { uint64_t a = mkkey(fmono(x), c0 + ob + 1); if (a >= th) { int p = atomicAdd(&sCnt, 1); if (p < CAPC) cand[p] = a; } }
        x = v.z; if ((bm[(ob+2) >> 5] >> ((ob+2) & 31)) & 1u) x = (x < 0.f) ? x * rp : x * inv_rp;
        { uint64_t a = mkkey(fmono(x), c0 + ob + 2); if (a >= th) { int p = atomicAdd(&sCnt, 1); if (p < CAPC) cand[p] = a; } }
        x = v.w; if ((bm[(ob+3) >> 5] >> ((ob+3) & 31)) & 1u) x = (x < 0.f) ? x * rp : x * inv_rp;
        { uint64_t a = mkkey(fmono(x), c0 + ob + 3); if (a >= th) { int p = atomicAdd(&sCnt, 1); if (p < CAPC) cand[p] = a; } }
    }
    for (int o = tail0 + tid; o < len; o += K1T) {
        uint64_t a = keyAt(o);
        if (a >= th) { int p = atomicAdd(&sCnt, 1); if (p < CAPC) cand[p] = a; }
    }
    __syncthreads();
    int cnt2 = sCnt;

    // ---- sound fallback if collect overflowed (dead on Gaussian data) ----
    if (cnt2 > CAPC) {
        uint64_t loK = th, hiK = ~0ull, thF = th;
        for (int it = 0; it < 64; ++it) {
            uint64_t mid = loK + ((hiK - loK) >> 1);
            if (mid == loK) { thF = hiK; break; }
            if (tid == 0) sCnt2 = 0;
            __syncthreads();
            int lc = 0;
            for (int o = tid; o < len; o += K1T) lc += (int)(keyAt(o) >= mid);
            #pragma unroll
            for (int off = 32; off; off >>= 1) lc += __shfl_down(lc, off);
            if (lane == 0) atomicAdd(&sCnt2, lc);
            __syncthreads();
            int c = sCnt2;
            __syncthreads();
            if (c >= 64 && c <= CAPC) { thF = mid; break; }
            if (c > CAPC) loK = mid; else hiK = mid;
        }
        if (tid == 0) sCnt = 0;
        __syncthreads();
        for (int o = tid; o < len; o += K1T) {
            uint64_t a = keyAt(o);
            if (a >= thF) { int p = atomicAdd(&sCnt, 1); if (p < CAPC) cand[p] = a; }
        }
        __syncthreads();
        cnt2 = min(sCnt, CAPC);
    }

    // ---- rank-select -> SORTED top-64 ----
    for (int t = tid; t < cnt2; t += K1T) {
        const uint64_t ki = cand[t];
        int r = 0;
        int j = 0;
        for (; j + 8 <= cnt2; j += 8) {
            uint64_t a0 = cand[j],   a1 = cand[j+1], a2 = cand[j+2], a3 = cand[j+3];
            uint64_t a4 = cand[j+4], a5 = cand[j+5], a6 = cand[j+6], a7 = cand[j+7];
            r += (int)(a0 > ki) + (int)(a1 > ki) + (int)(a2 > ki) + (int)(a3 > ki)
               + (int)(a4 > ki) + (int)(a5 > ki) + (int)(a6 > ki) + (int)(a7 > ki);
        }
        for (; j < cnt2; ++j) r += (int)(cand[j] > ki);
        if (r < 64) top64[r] = ki;
    }
    __syncthreads();

    // ---- publish slot (line-padded; single writer per cache line) ----
    uint64_t* slot = slots + ((size_t)row * SPLITS + sp) * SLOTW;
    if (tid < 64) slot[tid] = top64[tid];
    if (tid == 0) slot[64] = (uint64_t)__float_as_uint(sSv);
    __syncthreads();                      // all waves drain stores (vmcnt) to L2

    // ---- election: last block of this row proceeds to merge/finale ----
    if (tid == 0) {
        __threadfence();                  // write-back L2 (slot dirty lines -> device scope)
        sOld = atomicAdd(&cnt[row], 1);
    }
    __syncthreads();
    if (sOld != SPLITS - 1) return;

    // ================= inlined k2 (elected block only) =================
    __threadfence();
    const uint64_t* base = slots + (size_t)row * SPLITS * SLOTW;
    const uint64_t myk = base[(tid >> 6) * SLOTW + (tid & 63)];
    ck[tid] = myk;
    if (tid == 0) {
        float S = 0.0f;
        #pragma unroll
        for (int j = 0; j < SPLITS; ++j) S += __uint_as_float((unsigned)base[j * SLOTW + 64]);
        sS2 = S;
    }
    if (tid < 64) tk[tid] = 0ull;
    __syncthreads();

    // global rank = own position + #greater in each other sorted (desc) list
    {
        const int j = tid >> 6;
        int r = tid & 63;
        #pragma unroll
        for (int o = 0; o < SPLITS; ++o) {
            if (o == j) continue;
            const uint64_t* ls = &ck[o * 64];
            int lo = 0, hi = 64;
            while (lo < hi) {
                int mid = (lo + hi) >> 1;
                if (ls[mid] > myk) lo = mid + 1; else hi = mid;
            }
            r += lo;
        }
        if (r < 64) tk[r] = myk;
    }

    // ---- zero the WHOLE probs row (sole writer of this row's output) ----
    {
        float* orow = out_probs + (size_t)row * VV;
        const int padr = (4 - (row & 3)) & 3;
        const int n4r = (VV - padr) >> 2;
        const int tailr = padr + 4 * n4r;
        float4* o4r = (float4*)(orow + padr);
        const float4 z4 = make_float4(0.f, 0.f, 0.f, 0.f);
        for (int o = tid; o < padr; o += K1T) orow[o] = 0.0f;
        for (int k = tid; k < n4r; k += K1T) o4r[k] = z4;
        for (int o = tailr + tid; o < VV; o += K1T) orow[o] = 0.0f;
    }
    __syncthreads();                      // tk visible + zero-stores drained

    // ---- finale: top-p cutoff, temperature softmax, scatter, gumbel argmax ----
    if (tid < 64) {
        const float top_p = toppp[0];
        const float temp = tempp[0];
        int K = topkp[0]; K = min(max(K, 1), 64);
        const float Ssum = sS2;
        const uint64_t k64 = tk[lane];
        const float vl = unmono((unsigned)(k64 >> 32));
        const int ci = (int)(~(unsigned)(k64 & 0xFFFFFFFFu));
        bool act = (lane < K);
        float e = act ? expf(vl - CEXP) / Ssum : 0.0f;
        float cum = e;
        #pragma unroll
        for (int off2 = 1; off2 < 64; off2 <<= 1) {
            float pv = __shfl_up(cum, off2);
            if (lane >= off2) cum += pv;
        }
        unsigned long long bal = __ballot(act && (cum <= top_p));
        int n = (int)__popcll(bal);
        if (n < 1) n = 1;   // rank-0 always kept
        const float v0 = __shfl(vl, 0);
        const float invT = 1.0f / fmaxf(temp, 1e-5f);
        bool keep = (lane < n);
        float w = keep ? expf((vl - v0) * invT) : 0.0f;
        float Z = w;
        #pragma unroll
        for (int off2 = 32; off2; off2 >>= 1) Z += __shfl_xor(Z, off2);
        float p = keep ? (w / Z) : 0.0f;
        if (keep) out_probs[(size_t)row * VV + ci] = p;
        float ratio = -1.0f;
        if (keep) ratio = p / (-logf(u[(size_t)row * VV + ci]));
        int bi = keep ? ci : 0x7FFFFFFF;
        #pragma unroll
        for (int off2 = 32; off2; off2 >>= 1) {
            float orat = __shfl_xor(ratio, off2);
            int oidx = __shfl_xor(bi, off2);
            if (orat > ratio || (orat == ratio && oidx < bi)) { ratio = orat; bi = oidx; }
        }
        if (lane == 0) out_idx[row] = (float)bi;
    }
}

extern "C" void kernel_launch(void* const* d_in, const int* in_sizes, int n_in,
                              void* d_out, int out_size, void* d_ws, size_t ws_size,
                              hipStream_t stream) {
    const float* logits = (const float*)d_in[0];
    const int*   prev   = (const int*)d_in[1];
    const float* u      = (const float*)d_in[2];
    const float* topp   = (const float*)d_in[3];
    const float* rp     = (const float*)d_in[4];
    const float* temp   = (const float*)d_in[5];
    const int*   topk   = (const int*)d_in[6];

    const int B  = in_sizes[0] / VV;
    const int Hp = in_sizes[1] / B;

    // ws: cnt[B] ints at 0 (memset to 0 each call); slots at +4096
    char* ws = (char*)d_ws;
    int* cnt = (int*)ws;
    uint64_t* slots = (uint64_t*)(ws + 4096);

    float* out = (float*)d_out;
    hipMemsetAsync(cnt, 0, (size_t)B * sizeof(int), stream);
    pp_fused<<<dim3(SPLITS, B), K1T, 0, stream>>>(
        logits, prev, rp, u, topp, temp, topk, slots, cnt, out, out + B, Hp);
}

// Round 14
// 35.919 us; speedup vs baseline: 4.8532x; 4.8532x over previous
//
#include <hip/hip_runtime.h>
#include <cfloat>
#include <cmath>
#include <cstdint>

#define VV 50257
#define SPLITS 8
#define CHUNKA 6284                      // multiple of 4; 8*6284 >= 50257; last len 6269
#define BMW ((CHUNKA + 31) / 32)         // 197
#define CAPC 512
#define K1T 512
#define NWAVE (K1T / 64)                 // 8
#define K2T 512                          // = SPLITS*64 keys, one thread each
#define CEXP 28.0f                       // fixed softmax shift; |penalized logit| <~ 23

__device__ __forceinline__ unsigned fmono(float f) {
    unsigned b = __float_as_uint(f);
    return b ^ (((int)b < 0) ? 0xFFFFFFFFu : 0x80000000u);
}
__device__ __forceinline__ float unmono(unsigned m) {
    unsigned b = (m & 0x80000000u) ? (m ^ 0x80000000u) : ~m;
    return __uint_as_float(b);
}
// sortable key: value-desc, tie -> smaller index first; > 0 for finite x
__device__ __forceinline__ uint64_t mkkey(unsigned mono, int idx) {
    return ((uint64_t)mono << 32) | (unsigned)(~idx);
}

// K1: per (row, chunk): pass A = {float4 load, fused zero-store, penalize,
// exp-sum(CEXP), top-1 max}; theta = 64th of 512 thread maxima (wave bitonic
// + binsearch rank; exact, theta <= v64); pass B = L2-hot vectorized collect
// >= theta; rank-select -> sorted top-64 keys to private slots.
__global__ __launch_bounds__(K1T) void pp_k1(
    const float* __restrict__ logits, const int* __restrict__ prev,
    const float* __restrict__ rpp,
    float* __restrict__ ps, uint64_t* __restrict__ gkey,
    float* __restrict__ out_probs, int Hp)
{
    const int sp = blockIdx.x, row = blockIdx.y;
    const int tid = threadIdx.x, lane = tid & 63, wid = tid >> 6;
    const int c0 = sp * CHUNKA;
    const int c1 = min(VV, c0 + CHUNKA);
    const int len = c1 - c0;
    const float rp = rpp[0], inv_rp = 1.0f / rp;

    __shared__ unsigned bm[BMW];
    __shared__ uint64_t kls[K1T];        // NWAVE sorted (desc) 64-lists of maxima
    __shared__ uint64_t cand[CAPC];
    __shared__ uint64_t top64[64];
    __shared__ float red_s[NWAVE];
    __shared__ uint64_t sV64;
    __shared__ int sCnt, sCnt2;

    for (int i = tid; i < BMW; i += K1T) bm[i] = 0u;
    if (tid == 0) sCnt = 0;
    __syncthreads();

    // chunk-local prev-token bitmap (penalty idempotent w.r.t. duplicates)
    const int* prow = prev + (size_t)row * Hp;
    const int h4 = Hp >> 2;
    const int4* prow4 = (const int4*)prow;
    for (int i = tid; i < h4; i += K1T) {
        int4 t4 = prow4[i];
        int t;
        t = t4.x; if (t >= c0 && t < c1) { int o = t - c0; atomicOr(&bm[o >> 5], 1u << (o & 31)); }
        t = t4.y; if (t >= c0 && t < c1) { int o = t - c0; atomicOr(&bm[o >> 5], 1u << (o & 31)); }
        t = t4.z; if (t >= c0 && t < c1) { int o = t - c0; atomicOr(&bm[o >> 5], 1u << (o & 31)); }
        t = t4.w; if (t >= c0 && t < c1) { int o = t - c0; atomicOr(&bm[o >> 5], 1u << (o & 31)); }
    }
    for (int i = 4 * h4 + tid; i < Hp; i += K1T) {
        int t = prow[i];
        if (t >= c0 && t < c1) { int o = t - c0; atomicOr(&bm[o >> 5], 1u << (o & 31)); }
    }
    __syncthreads();

    const float* lrow = logits + (size_t)row * VV;
    float* orow = out_probs + (size_t)row * VV;
    // (row*VV + c0) mod 4 == row mod 4  (VV%4==1, CHUNKA%4==0); peel to 16B
    const int pad = (4 - (row & 3)) & 3;
    const int n4 = (len - pad) >> 2;
    const int tail0 = pad + 4 * n4;                 // chunk-local
    const float4* l4 = (const float4*)(lrow + c0 + pad);
    float4* o4 = (float4*)(orow + c0 + pad);
    const float4 z4 = make_float4(0.f, 0.f, 0.f, 0.f);

    // penalized key at chunk-local offset o (L2-hot helper)
    auto keyAt = [&](int o) -> uint64_t {
        float x = lrow[c0 + o];
        if ((bm[o >> 5] >> (o & 31)) & 1u) x = (x < 0.f) ? x * rp : x * inv_rp;
        return mkkey(fmono(x), c0 + o);
    };

    // ---- pass A: {load, fused zero-store, penalize, exp-sum, top-1} ----
    float s = 0.0f;
    uint64_t k0 = 0ull;
    for (int o = tid; o < pad; o += K1T) {
        float x = lrow[c0 + o];
        orow[c0 + o] = 0.0f;
        if ((bm[o >> 5] >> (o & 31)) & 1u) x = (x < 0.f) ? x * rp : x * inv_rp;
        s += __expf(x - CEXP);
        uint64_t a = mkkey(fmono(x), c0 + o);
        k0 = (a > k0) ? a : k0;
    }
    #pragma unroll 4
    for (int k = tid; k < n4; k += K1T) {
        float4 v = l4[k];
        o4[k] = z4;                      // normal store; L2-absorbed, drains in bg
        const int ob = pad + 4 * k;
        float x;
        x = v.x; if ((bm[(ob+0) >> 5] >> ((ob+0) & 31)) & 1u) x = (x < 0.f) ? x * rp : x * inv_rp;
        s += __expf(x - CEXP);
        { uint64_t a = mkkey(fmono(x), c0 + ob + 0); k0 = (a > k0) ? a : k0; }
        x = v.y; if ((bm[(ob+1) >> 5] >> ((ob+1) & 31)) & 1u) x = (x < 0.f) ? x * rp : x * inv_rp;
        s += __expf(x - CEXP);
        { uint64_t a = mkkey(fmono(x), c0 + ob + 1); k0 = (a > k0) ? a : k0; }
        x = v.z; if ((bm[(ob+2) >> 5] >> ((ob+2) & 31)) & 1u) x = (x < 0.f) ? x * rp : x * inv_rp;
        s += __expf(x - CEXP);
        { uint64_t a = mkkey(fmono(x), c0 + ob + 2); k0 = (a > k0) ? a : k0; }
        x = v.w; if ((bm[(ob+3) >> 5] >> ((ob+3) & 31)) & 1u) x = (x < 0.f) ? x * rp : x * inv_rp;
        s += __expf(x - CEXP);
        { uint64_t a = mkkey(fmono(x), c0 + ob + 3); k0 = (a > k0) ? a : k0; }
    }
    for (int o = tail0 + tid; o < len; o += K1T) {
        float x = lrow[c0 + o];
        orow[c0 + o] = 0.0f;
        if ((bm[o >> 5] >> (o & 31)) & 1u) x = (x < 0.f) ? x * rp : x * inv_rp;
        s += __expf(x - CEXP);
        uint64_t a = mkkey(fmono(x), c0 + o);
        k0 = (a > k0) ? a : k0;
    }

    // ---- exp-sum wave reduce ----
    #pragma unroll
    for (int off = 32; off; off >>= 1) s += __shfl_down(s, off);
    if (lane == 0) red_s[wid] = s;

    // ---- wave bitonic sort of k0 across 64 lanes (registers only) ----
    {
        uint64_t v = k0;
        #pragma unroll
        for (int kk = 2; kk <= 64; kk <<= 1) {
            #pragma unroll
            for (int j = kk >> 1; j > 0; j >>= 1) {
                uint64_t o = __shfl_xor(v, j);
                bool lower = (lane & j) == 0;
                bool asc = (lane & kk) == 0;
                uint64_t mx = (v > o) ? v : o;
                uint64_t mn = (v > o) ? o : v;
                v = (lower != asc) ? mx : mn;
            }
        }
        kls[wid * 64 + (63 - lane)] = v;   // store descending
    }
    __syncthreads();

    const int slot = row * SPLITS + sp;
    if (tid == 0) {
        float S = red_s[0];
        #pragma unroll
        for (int w = 1; w < NWAVE; ++w) S += red_s[w];
        ps[slot] = S;
    }

    // ---- theta = 64th-largest thread max: binsearch-rank over 8 sorted lists ----
    {
        const uint64_t ki = kls[tid];
        int r = tid & 63;                 // rank within own (desc) list
        const int j = tid >> 6;
        #pragma unroll
        for (int o = 0; o < NWAVE; ++o) {
            if (o == j) continue;
            const uint64_t* ls = &kls[o * 64];
            int lo = 0, hi = 64;
            while (lo < hi) {             // first idx with ls[idx] < ki (keys unique)
                int mid = (lo + hi) >> 1;
                if (ls[mid] > ki) lo = mid + 1; else hi = mid;
            }
            r += lo;
        }
        if (r == 63) sV64 = ki;           // exactly one thread matches
    }
    __syncthreads();
    const uint64_t th = sV64;

    // ---- pass B: collect >= theta (L2-hot vectorized re-read) ----
    for (int o = tid; o < pad; o += K1T) {
        uint64_t a = keyAt(o);
        if (a >= th) { int p = atomicAdd(&sCnt, 1); if (p < CAPC) cand[p] = a; }
    }
    #pragma unroll 2
    for (int k = tid; k < n4; k += K1T) {
        float4 v = l4[k];
        const int ob = pad + 4 * k;
        float x;
        x = v.x; if ((bm[(ob+0) >> 5] >> ((ob+0) & 31)) & 1u) x = (x < 0.f) ? x * rp : x * inv_rp;
        { uint64_t a = mkkey(fmono(x), c0 + ob + 0); if (a >= th) { int p = atomicAdd(&sCnt, 1); if (p < CAPC) cand[p] = a; } }
        x = v.y; if ((bm[(ob+1) >> 5] >> ((ob+1) & 31)) & 1u) x = (x < 0.f) ? x * rp : x * inv_rp;
        { uint64_t a = mkkey(fmono(x), c0 + ob + 1); if (a >= th) { int p = atomicAdd(&sCnt, 1); if (p < CAPC) cand[p] = a; } }
        x = v.z; if ((bm[(ob+2) >> 5] >> ((ob+2) & 31)) & 1u) x = (x < 0.f) ? x * rp : x * inv_rp;
        { uint64_t a = mkkey(fmono(x), c0 + ob + 2); if (a >= th) { int p = atomicAdd(&sCnt, 1); if (p < CAPC) cand[p] = a; } }
        x = v.w; if ((bm[(ob+3) >> 5] >> ((ob+3) & 31)) & 1u) x = (x < 0.f) ? x * rp : x * inv_rp;
        { uint64_t a = mkkey(fmono(x), c0 + ob + 3); if (a >= th) { int p = atomicAdd(&sCnt, 1); if (p < CAPC) cand[p] = a; } }
    }
    for (int o = tail0 + tid; o < len; o += K1T) {
        uint64_t a = keyAt(o);
        if (a >= th) { int p = atomicAdd(&sCnt, 1); if (p < CAPC) cand[p] = a; }
    }
    __syncthreads();
    int cnt = sCnt;

    // ---- sound fallback if collect overflowed (dead on Gaussian data) ----
    if (cnt > CAPC) {
        uint64_t loK = th, hiK = ~0ull, thF = th;
        for (int it = 0; it < 64; ++it) {
            uint64_t mid = loK + ((hiK - loK) >> 1);
            if (mid == loK) { thF = hiK; break; }
            if (tid == 0) sCnt2 = 0;
            __syncthreads();
            int lc = 0;
            for (int o = tid; o < len; o += K1T) lc += (int)(keyAt(o) >= mid);
            #pragma unroll
            for (int off = 32; off; off >>= 1) lc += __shfl_down(lc, off);
            if (lane == 0) atomicAdd(&sCnt2, lc);
            __syncthreads();
            int c = sCnt2;
            __syncthreads();
            if (c >= 64 && c <= CAPC) { thF = mid; break; }
            if (c > CAPC) loK = mid; else hiK = mid;
        }
        if (tid == 0) sCnt = 0;
        __syncthreads();
        for (int o = tid; o < len; o += K1T) {
            uint64_t a = keyAt(o);
            if (a >= thF) { int p = atomicAdd(&sCnt, 1); if (p < CAPC) cand[p] = a; }
        }
        __syncthreads();
        cnt = min(sCnt, CAPC);
    }

    // ---- rank-select -> SORTED top-64 (all-pairs over ~70-100 candidates) ----
    for (int t = tid; t < cnt; t += K1T) {
        const uint64_t ki = cand[t];
        int r = 0;
        int j = 0;
        for (; j + 8 <= cnt; j += 8) {
            uint64_t a0 = cand[j],   a1 = cand[j+1], a2 = cand[j+2], a3 = cand[j+3];
            uint64_t a4 = cand[j+4], a5 = cand[j+5], a6 = cand[j+6], a7 = cand[j+7];
            r += (int)(a0 > ki) + (int)(a1 > ki) + (int)(a2 > ki) + (int)(a3 > ki)
               + (int)(a4 > ki) + (int)(a5 > ki) + (int)(a6 > ki) + (int)(a7 > ki);
        }
        for (; j < cnt; ++j) r += (int)(cand[j] > ki);
        if (r < 64) top64[r] = ki;
    }
    __syncthreads();
    if (tid < 64) gkey[(size_t)slot * 64 + tid] = top64[tid];
}

// K2: per row: S = sum of partials; rank 8 sorted 64-lists via binary search;
// finale (top-p, temperature softmax, scatter, gumbel argmax).
__global__ __launch_bounds__(K2T) void pp_k2(
    const float* __restrict__ u, const float* __restrict__ toppp,
    const float* __restrict__ tempp, const int* __restrict__ topkp,
    const float* __restrict__ ps, const uint64_t* __restrict__ gkey,
    float* __restrict__ out_idx, float* __restrict__ out_probs)
{
    const int row = blockIdx.x, tid = threadIdx.x;
    __shared__ uint64_t ck[SPLITS * 64];
    __shared__ uint64_t tk[64];
    __shared__ float sS;

    ck[tid] = gkey[(size_t)row * (SPLITS * 64) + tid];
    if (tid == 0) {
        float S = 0.0f;
        #pragma unroll
        for (int j = 0; j < SPLITS; ++j) S += ps[row * SPLITS + j];
        sS = S;
    }
    __syncthreads();

    // global rank = own position + #greater in each other sorted (desc) list
    {
        const int j = tid >> 6;          // own list
        const uint64_t ki = ck[tid];
        int r = tid & 63;                // rank within own list
        #pragma unroll
        for (int o = 0; o < SPLITS; ++o) {
            if (o == j) continue;
            const uint64_t* ls = &ck[o * 64];
            int lo = 0, hi = 64;
            while (lo < hi) {            // first idx with ls[idx] < ki (keys unique)
                int mid = (lo + hi) >> 1;
                if (ls[mid] > ki) lo = mid + 1; else hi = mid;
            }
            r += lo;
        }
        if (r < 64) tk[r] = ki;
    }
    __syncthreads();

    // finale: top-p cutoff, temperature softmax, scatter, gumbel argmax
    if (tid < 64) {
        const int lane = tid;
        const float top_p = toppp[0];
        const float temp = tempp[0];
        int K = topkp[0]; K = min(max(K, 1), 64);
        const float Ssum = sS;
        const uint64_t k64 = tk[lane];
        const float vl = unmono((unsigned)(k64 >> 32));
        const int ci = (int)(~(unsigned)(k64 & 0xFFFFFFFFu));
        bool act = (lane < K);
        float e = act ? expf(vl - CEXP) / Ssum : 0.0f;
        float cum = e;
        #pragma unroll
        for (int off2 = 1; off2 < 64; off2 <<= 1) {
            float pv = __shfl_up(cum, off2);
            if (lane >= off2) cum += pv;
        }
        unsigned long long bal = __ballot(act && (cum <= top_p));
        int n = (int)__popcll(bal);
        if (n < 1) n = 1;   // rank-0 always kept
        const float v0 = __shfl(vl, 0);
        const float invT = 1.0f / fmaxf(temp, 1e-5f);
        bool keep = (lane < n);
        float w = keep ? expf((vl - v0) * invT) : 0.0f;
        float Z = w;
        #pragma unroll
        for (int off2 = 32; off2; off2 >>= 1) Z += __shfl_xor(Z, off2);
        float p = keep ? (w / Z) : 0.0f;
        if (keep) out_probs[(size_t)row * VV + ci] = p;
        float ratio = -1.0f;
        if (keep) ratio = p / (-logf(u[(size_t)row * VV + ci]));
        int bi = keep ? ci : 0x7FFFFFFF;
        #pragma unroll
        for (int off2 = 32; off2; off2 >>= 1) {
            float orat = __shfl_xor(ratio, off2);
            int oidx = __shfl_xor(bi, off2);
            if (orat > ratio || (orat == ratio && oidx < bi)) { ratio = orat; bi = oidx; }
        }
        if (lane == 0) out_idx[row] = (float)bi;
    }
}

extern "C" void kernel_launch(void* const* d_in, const int* in_sizes, int n_in,
                              void* d_out, int out_size, void* d_ws, size_t ws_size,
                              hipStream_t stream) {
    const float* logits = (const float*)d_in[0];
    const int*   prev   = (const int*)d_in[1];
    const float* u      = (const float*)d_in[2];
    const float* topp   = (const float*)d_in[3];
    const float* rp     = (const float*)d_in[4];
    const float* temp   = (const float*)d_in[5];
    const int*   topk   = (const int*)d_in[6];

    const int B  = in_sizes[0] / VV;
    const int Hp = in_sizes[1] / B;

    // workspace: ps[B*SPLITS] floats at 0; gkey[B*SPLITS*64] u64 at 16KB
    char* ws = (char*)d_ws;
    float* ps = (float*)ws;
    uint64_t* gkey = (uint64_t*)(ws + 16384);

    float* out = (float*)d_out;
    pp_k1<<<dim3(SPLITS, B), K1T, 0, stream>>>(
        logits, prev, rp, ps, gkey, out + B, Hp);
    pp_k2<<<B, K2T, 0, stream>>>(
        u, topp, temp, topk, ps, gkey, out, out + B);
}